// Round 4
// baseline (110.455 us; speedup 1.0000x reference)
//
#include <hip/hip_runtime.h>
#include <hip/hip_bf16.h>

// PairRE scoring: out[b,n] = -|| t_hat[n]*rt[b] - h_hat[b]*rh[b] ||_2
// B=512, N=2048, E=256.
//
// x(b,n) = dot([T^2 | T]_n , [rt^2 | -2*rt*Hh]_b) + c_b,
//   T = t/||t||, Hh = (h/||h||)*rh, c_b = ||Hh_b||^2.
//
// R8: ONE dispatch, flag-based producer/consumer (no cooperative sync --
// R6 showed cg::sync costs ~130us; R7 showed score prefetch depth is not
// on the critical path, so the remaining ~12us over the ~5us kernel
// roofline is dispatch machinery: two launch boundaries + full drain
// bubble between prep and score).
//
// Structure: grid (32,16), 256 thr. Producer blocks: by<4 own T-group
// g=bx*4+by (the 4 groups consumed by column bx -- same XCD as consumers
// since lin%8=bx%8); by==4 own A-group bx + cvec. 160 producers, zero
// redundancy. Every block then waits on the 6 group flags its tile needs
// and runs the verified R4 score body.
//
// Safety:
//  * Residency: 512 blocks <= 2/CU * 256 CU, enforced via
//    __launch_bounds__(256,2) (VGPR<=256, LDS=0) -> all blocks co-resident
//    independent of dispatch order; producers never wait before flagging.
//  * Flags live in the workspace (unconditionally re-poisoned each
//    iteration by the harness fill -- which conveniently RESETS them).
//    "done" = 64-bit magic with two distinct 32-bit words: no memset-style
//    repeating fill pattern can alias it. If the fill were ever skipped,
//    stale flags are benign (prep output is bit-deterministic).
//  * Coherence per G16 (no XCD placement assumption): producer does
//    __syncthreads + agent-scope RELEASE flag store (L2 writeback);
//    consumers poll with relaxed agent-scope loads (cache-bypassing),
//    then __threadfence() (invalidate) before fragment reads. cvec is
//    padded to one 128B line per producer block; flags 128B apart.
// Numerics bit-identical to R4/R7 (absmax 0.0078125 expected unchanged).

#define B_DIM 512
#define N_DIM 2048
#define E_DIM 256
#define K_DIM 512
#define NSTEP 16        // K/32 MFMA k-steps
#define FRAG_US 512     // ushorts per packed fragment (64 lanes * 8)

#define FLAG_VAL 0x9E3779B985EBCA6BULL   // two distinct 32-bit words
#define NFLAGS 160                        // 128 T-groups + 32 A-groups
#define FLAG_STRIDE 16                    // ulongs per slot = 128 B

typedef __attribute__((ext_vector_type(8))) __bf16 bf16x8;
typedef __attribute__((ext_vector_type(4))) float f32x4;

__device__ inline ushort f2bf(float x) {
    __hip_bfloat16 h = __float2bfloat16(x);   // RNE
    union { __hip_bfloat16 b; ushort u; } cv_; cv_.b = h; return cv_.u;
}

__device__ inline float wave_sum(float v) {
#pragma unroll
    for (int m = 1; m < 64; m <<= 1) v += __shfl_xor(v, m, 64);
    return v;
}

// cvec padded: one 128B line (32 floats) per A-group, only first 16 used.
__device__ __forceinline__ int cv_idx(int b) { return ((b >> 4) << 5) | (b & 15); }

// ---------------- prep bodies (identical numerics to R4/R7) -------------
// Packed addr for row r=g*16+m, k=c*8+j (c=s*4+q): dst=((g*16+s)*64+q*16+m)*8
// Lane writes k0=lane*8 .. +7  ->  s=lane>>2, q=lane&3.
__device__ __forceinline__ void prep_T_row(const float* __restrict__ tail,
        ushort* __restrict__ Tbig, int n, int lane) {
    const int s_ = lane >> 2, q = lane & 3;
    const int k0 = lane * 8;
    const bool sqr = (k0 < E_DIM);
    const int e0 = k0 & (E_DIM - 1);
    const float* row = tail + (size_t)n * E_DIM;
    const float4 v4 = ((const float4*)row)[lane];
    const float s = wave_sum(v4.x * v4.x + v4.y * v4.y + v4.z * v4.z + v4.w * v4.w);
    const float inv = 1.0f / fmaxf(sqrtf(s), 1e-12f);
    const float4 f0 = *(const float4*)(row + e0);
    const float4 f1 = *(const float4*)(row + e0 + 4);
    const float v[8] = {f0.x, f0.y, f0.z, f0.w, f1.x, f1.y, f1.z, f1.w};
    ushort u[8];
#pragma unroll
    for (int j = 0; j < 8; ++j) {
        float x = v[j] * inv;
        if (sqr) x *= x;
        u[j] = f2bf(x);
    }
    const int g = n >> 4, m = n & 15;
    *(uint4*)(Tbig + (size_t)((g * 16 + s_) * 64 + q * 16 + m) * 8) = *(const uint4*)u;
}

__device__ __forceinline__ void prep_A_row(const float* __restrict__ head,
        const float* __restrict__ rel, const int* __restrict__ rid,
        ushort* __restrict__ Abig, float* __restrict__ cvecP, int b, int lane) {
    const int s_ = lane >> 2, q = lane & 3;
    const int k0 = lane * 8;
    const bool sqr = (k0 < E_DIM);
    const int e0 = k0 & (E_DIM - 1);
    const int id = rid[b];
    const float* hrow  = head + (size_t)b * E_DIM;
    const float* rhrow = rel + (size_t)id * (2 * E_DIM);
    const float* rtrow = rhrow + E_DIM;
    const float4 h4  = ((const float4*)hrow)[lane];
    const float4 rh4 = ((const float4*)rhrow)[lane];
    const float s1 = wave_sum(h4.x * h4.x + h4.y * h4.y + h4.z * h4.z + h4.w * h4.w);
    const float inv = 1.0f / fmaxf(sqrtf(s1), 1e-12f);
    const float p0 = h4.x * inv * rh4.x, p1 = h4.y * inv * rh4.y;
    const float p2 = h4.z * inv * rh4.z, p3 = h4.w * inv * rh4.w;
    const float s2 = wave_sum(p0 * p0 + p1 * p1 + p2 * p2 + p3 * p3);
    if (lane == 0) cvecP[cv_idx(b)] = s2;

    const float4 rt0 = *(const float4*)(rtrow + e0);
    const float4 rt1 = *(const float4*)(rtrow + e0 + 4);
    const float rt[8] = {rt0.x, rt0.y, rt0.z, rt0.w, rt1.x, rt1.y, rt1.z, rt1.w};
    float v[8];
    if (sqr) {
#pragma unroll
        for (int j = 0; j < 8; ++j) v[j] = rt[j] * rt[j];
    } else {
        const float4 h0 = *(const float4*)(hrow + e0);
        const float4 h1 = *(const float4*)(hrow + e0 + 4);
        const float4 r0 = *(const float4*)(rhrow + e0);
        const float4 r1 = *(const float4*)(rhrow + e0 + 4);
        const float hh[8] = {h0.x, h0.y, h0.z, h0.w, h1.x, h1.y, h1.z, h1.w};
        const float rr[8] = {r0.x, r0.y, r0.z, r0.w, r1.x, r1.y, r1.z, r1.w};
#pragma unroll
        for (int j = 0; j < 8; ++j) v[j] = -2.0f * rt[j] * (hh[j] * inv * rr[j]);
    }
    ushort u[8];
#pragma unroll
    for (int j = 0; j < 8; ++j) u[j] = f2bf(v[j]);
    const int g = b >> 4, m = b & 15;
    *(uint4*)(Abig + (size_t)((g * 16 + s_) * 64 + q * 16 + m) * 8) = *(const uint4*)u;
}

// ---------------- score body (identical to R4; cvec index padded) -------
// wave wv of block (p_n, b_super): gA = b_super*2 + (wv&1);
// gT0 = p_n*4 + (wv>>1)*2, +1. A stream shared by waves {wv,wv^2}, T by
// {wv,wv^1} -> L1 dedup. gridDim.x=32 % 8 == 0 -> all 16 blocks sharing
// one p_n (and its T-groups) land on one XCD (perf heuristic only).
__device__ __forceinline__ void score_tile(const ushort* __restrict__ Tbig,
        const ushort* __restrict__ Abig, const float* __restrict__ cvecP,
        float* __restrict__ out, int p_n, int b_super, int wv, int lane) {
    const int gA  = b_super * 2 + (wv & 1);
    const int gT0 = p_n * 4 + (wv >> 1) * 2;

    const ushort* Ab  = Abig + (size_t)gA * NSTEP * FRAG_US + lane * 8;
    const ushort* Tb0 = Tbig + (size_t)gT0 * NSTEP * FRAG_US + lane * 8;
    const ushort* Tb1 = Tb0 + (size_t)NSTEP * FRAG_US;

    f32x4 acc0 = {0.f, 0.f, 0.f, 0.f}, acc1 = {0.f, 0.f, 0.f, 0.f};

    bf16x8 a_c  = *(const bf16x8*)(Ab);
    bf16x8 b0_c = *(const bf16x8*)(Tb0);
    bf16x8 b1_c = *(const bf16x8*)(Tb1);
#pragma unroll
    for (int s = 0; s < NSTEP - 1; ++s) {
        const bf16x8 a_n  = *(const bf16x8*)(Ab  + (s + 1) * FRAG_US);
        const bf16x8 b0_n = *(const bf16x8*)(Tb0 + (s + 1) * FRAG_US);
        const bf16x8 b1_n = *(const bf16x8*)(Tb1 + (s + 1) * FRAG_US);
        acc0 = __builtin_amdgcn_mfma_f32_16x16x32_bf16(a_c, b0_c, acc0, 0, 0, 0);
        acc1 = __builtin_amdgcn_mfma_f32_16x16x32_bf16(a_c, b1_c, acc1, 0, 0, 0);
        a_c = a_n; b0_c = b0_n; b1_c = b1_n;
    }
    acc0 = __builtin_amdgcn_mfma_f32_16x16x32_bf16(a_c, b0_c, acc0, 0, 0, 0);
    acc1 = __builtin_amdgcn_mfma_f32_16x16x32_bf16(a_c, b1_c, acc1, 0, 0, 0);

    const int ml = lane & 15, qq = lane >> 4;
    const int b0 = gA * 16;
    const int n0 = gT0 * 16;
#pragma unroll
    for (int r = 0; r < 4; ++r) {
        const int b = b0 + qq * 4 + r;
        const float cb = cvecP[cv_idx(b)];
        out[(size_t)b * N_DIM + n0 + ml]      = -sqrtf(fmaxf(acc0[r] + cb, 0.f));
        out[(size_t)b * N_DIM + n0 + 16 + ml] = -sqrtf(fmaxf(acc1[r] + cb, 0.f));
    }
}

__device__ __forceinline__ void wait_flag(const unsigned long long* p) {
    while (__hip_atomic_load(p, __ATOMIC_RELAXED, __HIP_MEMORY_SCOPE_AGENT)
           != FLAG_VAL) {
        __builtin_amdgcn_s_sleep(2);
    }
}

// ---------------- R8: single dispatch, flags ----------------
__global__ __launch_bounds__(256, 2) void fused1_kernel(
        const float* __restrict__ head, const float* __restrict__ tail,
        const float* __restrict__ rel,  const int* __restrict__ rid,
        ushort* __restrict__ Tbig, ushort* __restrict__ Abig,
        float* __restrict__ cvecP, unsigned long long* __restrict__ flags,
        float* __restrict__ out) {
    const int tid = threadIdx.x, lane = tid & 63, wv = tid >> 6;
    const int bx = blockIdx.x, by = blockIdx.y;   // (32, 16)

    // ---- producer phase (160 of 512 blocks) ----
    if (by < 4) {
        // T-group g: produced on the same XCD its consumers occupy
        // (lin%8 = bx%8 for every by).
        const int g = bx * 4 + by;
#pragma unroll
        for (int r = 0; r < 4; ++r)
            prep_T_row(tail, Tbig, g * 16 + wv + 4 * r, lane);
        __syncthreads();   // all 4 waves' stores complete (vmcnt drained)
        if (tid == 0)
            __hip_atomic_store(&flags[(size_t)g * FLAG_STRIDE], FLAG_VAL,
                               __ATOMIC_RELEASE, __HIP_MEMORY_SCOPE_AGENT);
    } else if (by == 4) {
        const int gA = bx;
#pragma unroll
        for (int r = 0; r < 4; ++r)
            prep_A_row(head, rel, rid, Abig, cvecP, gA * 16 + wv + 4 * r, lane);
        __syncthreads();
        if (tid == 0)
            __hip_atomic_store(&flags[(size_t)(128 + gA) * FLAG_STRIDE], FLAG_VAL,
                               __ATOMIC_RELEASE, __HIP_MEMORY_SCOPE_AGENT);
    }

    // ---- wait for the 6 groups this block's tile consumes ----
    if (tid == 0) {
        const int gT0 = bx * 4;
        wait_flag(&flags[(size_t)(gT0 + 0) * FLAG_STRIDE]);
        wait_flag(&flags[(size_t)(gT0 + 1) * FLAG_STRIDE]);
        wait_flag(&flags[(size_t)(gT0 + 2) * FLAG_STRIDE]);
        wait_flag(&flags[(size_t)(gT0 + 3) * FLAG_STRIDE]);
        wait_flag(&flags[(size_t)(128 + by * 2 + 0) * FLAG_STRIDE]);
        wait_flag(&flags[(size_t)(128 + by * 2 + 1) * FLAG_STRIDE]);
    }
    __syncthreads();
    __threadfence();   // agent acquire: invalidate stale L1/L2 lines

    // ---- score phase (verified R4 body) ----
    score_tile(Tbig, Abig, cvecP, out, bx, by, wv, lane);
}

// ---------------- fallback (no workspace): pure fp32 ----------------
__device__ inline float block_reduce_sum_256(float v, float* buf) {
#pragma unroll
    for (int o = 32; o > 0; o >>= 1) v += __shfl_down(v, o, 64);
    const int lane = threadIdx.x & 63, wid = threadIdx.x >> 6;
    __syncthreads();
    if (lane == 0) buf[wid] = v;
    __syncthreads();
    return buf[0] + buf[1] + buf[2] + buf[3];
}

__global__ __launch_bounds__(256) void fallback_kernel(
        const float* __restrict__ head, const float* __restrict__ tail,
        const float* __restrict__ rel,  const int* __restrict__ rid,
        float* __restrict__ out) {
    __shared__ float Hh[E_DIM];
    __shared__ float RT[E_DIM];
    __shared__ float buf[4];
    const int b = blockIdx.x;
    const int tid = threadIdx.x;
    const float hv = head[(size_t)b * E_DIM + tid];
    const int id = rid[b];
    const float rh = rel[(size_t)id * (2 * E_DIM) + tid];
    const float rt = rel[(size_t)id * (2 * E_DIM) + E_DIM + tid];
    const float tot = block_reduce_sum_256(hv * hv, buf);
    const float inv = 1.0f / fmaxf(sqrtf(tot), 1e-12f);
    const float HhV = hv * inv * rh;
    Hh[tid] = HhV; RT[tid] = rt;
    const float c = block_reduce_sum_256(HhV * HhV, buf);
    __syncthreads();
    for (int n = tid; n < N_DIM; n += 256) {
        float S1 = 0.f, S2 = 0.f, Stt = 0.f;
        for (int e = 0; e < E_DIM; ++e) {
            const float tv = tail[(size_t)n * E_DIM + e];
            const float p = tv * RT[e];
            S1 += p * p; S2 += p * Hh[e]; Stt += tv * tv;
        }
        const float al = 1.0f / fmaxf(sqrtf(Stt), 1e-12f);
        const float x = al * al * S1 - 2.0f * al * S2 + c;
        out[(size_t)b * N_DIM + n] = -sqrtf(fmaxf(x, 0.f));
    }
}

extern "C" void kernel_launch(void* const* d_in, const int* in_sizes, int n_in,
                              void* d_out, int out_size, void* d_ws, size_t ws_size,
                              hipStream_t stream) {
    const float* head = (const float*)d_in[0];
    const float* tail = (const float*)d_in[1];
    const float* rel  = (const float*)d_in[2];
    const int*   rid  = (const int*)d_in[3];
    float* out = (float*)d_out;

    // workspace layout (all 128B-aligned):
    //   Tbig  : ushort[N*K]            2 MB
    //   Abig  : ushort[B*K]            512 KB
    //   cvecP : float[32*32]           4 KB   (one 128B line per A-group)
    //   flags : ulong[160*16]          20 KB  (one 128B line per flag)
    const size_t offA_us   = (size_t)N_DIM * K_DIM;
    const size_t offCP_b   = ((size_t)N_DIM + B_DIM) * K_DIM * sizeof(ushort);
    const size_t offFl_b   = offCP_b + 32 * 32 * sizeof(float);
    const size_t need      = offFl_b + (size_t)NFLAGS * FLAG_STRIDE * 8;

    if (ws_size >= need) {
        ushort* Tbig = (ushort*)d_ws;
        ushort* Abig = Tbig + offA_us;
        float*  cvecP = (float*)((char*)d_ws + offCP_b);
        unsigned long long* flags = (unsigned long long*)((char*)d_ws + offFl_b);
        dim3 grid(N_DIM / 64, B_DIM / 32);   // (32, 16) = 512 blocks
        fused1_kernel<<<grid, 256, 0, stream>>>(head, tail, rel, rid,
                                                Tbig, Abig, cvecP, flags, out);
    } else {
        fallback_kernel<<<B_DIM, 256, 0, stream>>>(head, tail, rel, rid, out);
    }
}

// Round 5
// 69.089 us; speedup vs baseline: 1.5987x; 1.5987x over previous
//
#include <hip/hip_runtime.h>
#include <hip/hip_bf16.h>

// PairRE scoring: out[b,n] = -|| t_hat[n]*rt[b] - h_hat[b]*rh[b] ||_2
// B=512, N=2048, E=256.
//
// x(b,n) = dot([T^2 | T]_n , [rt^2 | -2*rt*Hh]_b) + c_b,
//   T = t/||t||, Hh = (h/||h||)*rh, c_b = ||Hh_b||^2.
//
// R9: two-dispatch structure retained (verified 68us). Structural post-
// mortems: single-dispatch producer/consumer costs >=40us on this chip in
// ALL variants tried -- R5 redundant prep (41us kernel), R6 cg::sync
// (130us barrier), R8 flags+agent fences (50us of L2 writeback/invalidate
// + LLC polling). The implicit end-of-kernel release of a dispatch
// boundary (~2-4us) is the cheapest cross-XCD sync available. Cost model:
// dur = 41us harness fill (80-84% HBM peak, unconditional) + ~12us replay
// overhead + kernel time (~13us vs ~6us roofline).
// Change vs R7: score retiled from 16bx32n per wave (3 streams / 2 MFMA
// per k-step) to 32bx32n per wave (4 streams / 4 MFMA): loads per MFMA
// 1.5 -> 1.0, block-level L2 traffic 48 -> 32 MB, half the blocks.
// grid (32,8); gridDim.x%8==0 keeps T-column -> XCD grouping. Prep
// byte-identical. Numerics bit-identical (same MFMA chain & epilogue).

#define B_DIM 512
#define N_DIM 2048
#define E_DIM 256
#define K_DIM 512
#define NSTEP 16        // K/32 MFMA k-steps
#define FRAG_US 512     // ushorts per packed fragment (64 lanes * 8)

typedef __attribute__((ext_vector_type(8))) __bf16 bf16x8;
typedef __attribute__((ext_vector_type(4))) float f32x4;

__device__ inline ushort f2bf(float x) {
    __hip_bfloat16 h = __float2bfloat16(x);   // RNE
    union { __hip_bfloat16 b; ushort u; } cv_; cv_.b = h; return cv_.u;
}

__device__ inline float wave_sum(float v) {
#pragma unroll
    for (int m = 1; m < 64; m <<= 1) v += __shfl_xor(v, m, 64);
    return v;
}

// ---------------- prep bodies (identical numerics to R4/R7) -------------
// Packed addr for row r=g*16+m, k=c*8+j (c=s*4+q): dst=((g*16+s)*64+q*16+m)*8
// Lane writes k0=lane*8 .. +7  ->  s=lane>>2, q=lane&3.
__device__ __forceinline__ void prep_T_row(const float* __restrict__ tail,
        ushort* __restrict__ Tbig, int n, int lane) {
    const int s_ = lane >> 2, q = lane & 3;
    const int k0 = lane * 8;
    const bool sqr = (k0 < E_DIM);
    const int e0 = k0 & (E_DIM - 1);
    const float* row = tail + (size_t)n * E_DIM;
    const float4 v4 = ((const float4*)row)[lane];
    const float s = wave_sum(v4.x * v4.x + v4.y * v4.y + v4.z * v4.z + v4.w * v4.w);
    const float inv = 1.0f / fmaxf(sqrtf(s), 1e-12f);
    const float4 f0 = *(const float4*)(row + e0);
    const float4 f1 = *(const float4*)(row + e0 + 4);
    const float v[8] = {f0.x, f0.y, f0.z, f0.w, f1.x, f1.y, f1.z, f1.w};
    ushort u[8];
#pragma unroll
    for (int j = 0; j < 8; ++j) {
        float x = v[j] * inv;
        if (sqr) x *= x;
        u[j] = f2bf(x);
    }
    const int g = n >> 4, m = n & 15;
    *(uint4*)(Tbig + (size_t)((g * 16 + s_) * 64 + q * 16 + m) * 8) = *(const uint4*)u;
}

__device__ __forceinline__ void prep_A_row(const float* __restrict__ head,
        const float* __restrict__ rel, const int* __restrict__ rid,
        ushort* __restrict__ Abig, float* __restrict__ cvec, int b, int lane) {
    const int s_ = lane >> 2, q = lane & 3;
    const int k0 = lane * 8;
    const bool sqr = (k0 < E_DIM);
    const int e0 = k0 & (E_DIM - 1);
    const int id = rid[b];
    const float* hrow  = head + (size_t)b * E_DIM;
    const float* rhrow = rel + (size_t)id * (2 * E_DIM);
    const float* rtrow = rhrow + E_DIM;
    const float4 h4  = ((const float4*)hrow)[lane];
    const float4 rh4 = ((const float4*)rhrow)[lane];
    const float s1 = wave_sum(h4.x * h4.x + h4.y * h4.y + h4.z * h4.z + h4.w * h4.w);
    const float inv = 1.0f / fmaxf(sqrtf(s1), 1e-12f);
    const float p0 = h4.x * inv * rh4.x, p1 = h4.y * inv * rh4.y;
    const float p2 = h4.z * inv * rh4.z, p3 = h4.w * inv * rh4.w;
    const float s2 = wave_sum(p0 * p0 + p1 * p1 + p2 * p2 + p3 * p3);
    if (lane == 0) cvec[b] = s2;

    const float4 rt0 = *(const float4*)(rtrow + e0);
    const float4 rt1 = *(const float4*)(rtrow + e0 + 4);
    const float rt[8] = {rt0.x, rt0.y, rt0.z, rt0.w, rt1.x, rt1.y, rt1.z, rt1.w};
    float v[8];
    if (sqr) {
#pragma unroll
        for (int j = 0; j < 8; ++j) v[j] = rt[j] * rt[j];
    } else {
        const float4 h0 = *(const float4*)(hrow + e0);
        const float4 h1 = *(const float4*)(hrow + e0 + 4);
        const float4 r0 = *(const float4*)(rhrow + e0);
        const float4 r1 = *(const float4*)(rhrow + e0 + 4);
        const float hh[8] = {h0.x, h0.y, h0.z, h0.w, h1.x, h1.y, h1.z, h1.w};
        const float rr[8] = {r0.x, r0.y, r0.z, r0.w, r1.x, r1.y, r1.z, r1.w};
#pragma unroll
        for (int j = 0; j < 8; ++j) v[j] = -2.0f * rt[j] * (hh[j] * inv * rr[j]);
    }
    ushort u[8];
#pragma unroll
    for (int j = 0; j < 8; ++j) u[j] = f2bf(v[j]);
    const int g = b >> 4, m = b & 15;
    *(uint4*)(Abig + (size_t)((g * 16 + s_) * 64 + q * 16 + m) * 8) = *(const uint4*)u;
}

__global__ __launch_bounds__(256) void prep_kernel(
        const float* __restrict__ head, const float* __restrict__ tail,
        const float* __restrict__ rel,  const int* __restrict__ rid,
        ushort* __restrict__ Tbig, ushort* __restrict__ Abig,
        float* __restrict__ cvec) {
    const int tid = threadIdx.x, lane = tid & 63, wv = tid >> 6;
    const int w = blockIdx.x * 4 + wv;     // 0..2559
    if (w < N_DIM) prep_T_row(tail, Tbig, w, lane);
    else           prep_A_row(head, rel, rid, Abig, cvec, w - N_DIM, lane);
}

// ---------------- score: no LDS/barriers; 32b x 32n per wave ------------
// grid = (32, 8): blockIdx.x = p_n (64 n-cols), blockIdx.y = b_super (64
// b-rows). Wave wv -> (wr,wc) = (wv>>1, wv&1): A-groups gA0 =
// b_super*4 + wr*2 (+0,+1); T-groups gT0 = p_n*4 + wc*2 (+0,+1).
// 4 streams feed 4 MFMAs per k-step (loads/MFMA = 1.0 vs 1.5 in R4/R7).
// A streams shared by the 2 waves with equal wr, T streams by the 2 waves
// with equal wc -> L1 dedup. gridDim.x=32 % 8 == 0 -> the 8 blocks
// sharing one p_n column land on one XCD (perf heuristic only).
__global__ __launch_bounds__(256) void score_kernel(
        const ushort* __restrict__ Tbig, const ushort* __restrict__ Abig,
        const float* __restrict__ cvec, float* __restrict__ out) {
    const int tid = threadIdx.x, lane = tid & 63, wv = tid >> 6;
    const int p_n = blockIdx.x, b_super = blockIdx.y;
    const int wr = wv >> 1, wc = wv & 1;
    const int gA0 = b_super * 4 + wr * 2;
    const int gT0 = p_n * 4 + wc * 2;

    const ushort* Ab0 = Abig + (size_t)gA0 * NSTEP * FRAG_US + lane * 8;
    const ushort* Ab1 = Ab0 + (size_t)NSTEP * FRAG_US;
    const ushort* Tb0 = Tbig + (size_t)gT0 * NSTEP * FRAG_US + lane * 8;
    const ushort* Tb1 = Tb0 + (size_t)NSTEP * FRAG_US;

    f32x4 acc00 = {0.f, 0.f, 0.f, 0.f}, acc01 = {0.f, 0.f, 0.f, 0.f};
    f32x4 acc10 = {0.f, 0.f, 0.f, 0.f}, acc11 = {0.f, 0.f, 0.f, 0.f};

    bf16x8 a0_c = *(const bf16x8*)(Ab0);
    bf16x8 a1_c = *(const bf16x8*)(Ab1);
    bf16x8 t0_c = *(const bf16x8*)(Tb0);
    bf16x8 t1_c = *(const bf16x8*)(Tb1);
#pragma unroll
    for (int s = 0; s < NSTEP - 1; ++s) {
        const bf16x8 a0_n = *(const bf16x8*)(Ab0 + (s + 1) * FRAG_US);
        const bf16x8 a1_n = *(const bf16x8*)(Ab1 + (s + 1) * FRAG_US);
        const bf16x8 t0_n = *(const bf16x8*)(Tb0 + (s + 1) * FRAG_US);
        const bf16x8 t1_n = *(const bf16x8*)(Tb1 + (s + 1) * FRAG_US);
        acc00 = __builtin_amdgcn_mfma_f32_16x16x32_bf16(a0_c, t0_c, acc00, 0, 0, 0);
        acc01 = __builtin_amdgcn_mfma_f32_16x16x32_bf16(a0_c, t1_c, acc01, 0, 0, 0);
        acc10 = __builtin_amdgcn_mfma_f32_16x16x32_bf16(a1_c, t0_c, acc10, 0, 0, 0);
        acc11 = __builtin_amdgcn_mfma_f32_16x16x32_bf16(a1_c, t1_c, acc11, 0, 0, 0);
        a0_c = a0_n; a1_c = a1_n; t0_c = t0_n; t1_c = t1_n;
    }
    acc00 = __builtin_amdgcn_mfma_f32_16x16x32_bf16(a0_c, t0_c, acc00, 0, 0, 0);
    acc01 = __builtin_amdgcn_mfma_f32_16x16x32_bf16(a0_c, t1_c, acc01, 0, 0, 0);
    acc10 = __builtin_amdgcn_mfma_f32_16x16x32_bf16(a1_c, t0_c, acc10, 0, 0, 0);
    acc11 = __builtin_amdgcn_mfma_f32_16x16x32_bf16(a1_c, t1_c, acc11, 0, 0, 0);

    // Epilogue: C layout col=lane&15 (n), row=(lane>>4)*4+r (b).
    const int ml = lane & 15, qq = lane >> 4;
    const int n0 = gT0 * 16;
#pragma unroll
    for (int a = 0; a < 2; ++a) {
        const f32x4 accT0 = a ? acc10 : acc00;
        const f32x4 accT1 = a ? acc11 : acc01;
        const int b0 = (gA0 + a) * 16;
#pragma unroll
        for (int r = 0; r < 4; ++r) {
            const int b = b0 + qq * 4 + r;
            const float cb = cvec[b];
            out[(size_t)b * N_DIM + n0 + ml]      = -sqrtf(fmaxf(accT0[r] + cb, 0.f));
            out[(size_t)b * N_DIM + n0 + 16 + ml] = -sqrtf(fmaxf(accT1[r] + cb, 0.f));
        }
    }
}

// ---------------- fallback (no workspace): pure fp32 ----------------
__device__ inline float block_reduce_sum_256(float v, float* buf) {
#pragma unroll
    for (int o = 32; o > 0; o >>= 1) v += __shfl_down(v, o, 64);
    const int lane = threadIdx.x & 63, wid = threadIdx.x >> 6;
    __syncthreads();
    if (lane == 0) buf[wid] = v;
    __syncthreads();
    return buf[0] + buf[1] + buf[2] + buf[3];
}

__global__ __launch_bounds__(256) void fallback_kernel(
        const float* __restrict__ head, const float* __restrict__ tail,
        const float* __restrict__ rel,  const int* __restrict__ rid,
        float* __restrict__ out) {
    __shared__ float Hh[E_DIM];
    __shared__ float RT[E_DIM];
    __shared__ float buf[4];
    const int b = blockIdx.x;
    const int tid = threadIdx.x;
    const float hv = head[(size_t)b * E_DIM + tid];
    const int id = rid[b];
    const float rh = rel[(size_t)id * (2 * E_DIM) + tid];
    const float rt = rel[(size_t)id * (2 * E_DIM) + E_DIM + tid];
    const float tot = block_reduce_sum_256(hv * hv, buf);
    const float inv = 1.0f / fmaxf(sqrtf(tot), 1e-12f);
    const float HhV = hv * inv * rh;
    Hh[tid] = HhV; RT[tid] = rt;
    const float c = block_reduce_sum_256(HhV * HhV, buf);
    __syncthreads();
    for (int n = tid; n < N_DIM; n += 256) {
        float S1 = 0.f, S2 = 0.f, Stt = 0.f;
        for (int e = 0; e < E_DIM; ++e) {
            const float tv = tail[(size_t)n * E_DIM + e];
            const float p = tv * RT[e];
            S1 += p * p; S2 += p * Hh[e]; Stt += tv * tv;
        }
        const float al = 1.0f / fmaxf(sqrtf(Stt), 1e-12f);
        const float x = al * al * S1 - 2.0f * al * S2 + c;
        out[(size_t)b * N_DIM + n] = -sqrtf(fmaxf(x, 0.f));
    }
}

extern "C" void kernel_launch(void* const* d_in, const int* in_sizes, int n_in,
                              void* d_out, int out_size, void* d_ws, size_t ws_size,
                              hipStream_t stream) {
    const float* head = (const float*)d_in[0];
    const float* tail = (const float*)d_in[1];
    const float* rel  = (const float*)d_in[2];
    const int*   rid  = (const int*)d_in[3];
    float* out = (float*)d_out;

    const size_t needT = (size_t)N_DIM * K_DIM * sizeof(ushort);   // 2 MB
    const size_t needA = (size_t)B_DIM * K_DIM * sizeof(ushort);   // 512 KB
    const size_t needC = (size_t)B_DIM * sizeof(float);            // 2 KB
    if (ws_size >= needT + needA + needC) {
        ushort* Tbig = (ushort*)d_ws;
        ushort* Abig = Tbig + (size_t)N_DIM * K_DIM;
        float*  cvec = (float*)(Abig + (size_t)B_DIM * K_DIM);
        prep_kernel<<<(N_DIM + B_DIM) / 4, 256, 0, stream>>>(head, tail, rel, rid,
                                                             Tbig, Abig, cvec);
        dim3 grid(N_DIM / 64, B_DIM / 64);   // (32, 8) = 256 blocks
        score_kernel<<<grid, 256, 0, stream>>>(Tbig, Abig, cvec, out);
    } else {
        fallback_kernel<<<B_DIM, 256, 0, stream>>>(head, tail, rel, rid, out);
    }
}